// Round 5
// baseline (47.126 us; speedup 1.0000x reference)
//
#include <hip/hip_runtime.h>
#include <math.h>

#define BB 4096
#define DD 1024
#define KK 5
#define PP 1323
#define PTS_PER_THREAD 21   // 1323 = 63 * 21

// (2*pi)^(-3/2)
#define INV_2PI_POW15 0.06349363593424097f

// ---- head GEMM config ----
#define KSPL 4        // k-split (grid.y)
#define BK   256      // K per block
#define GR   16       // rows per block
#define NC   48       // padded output cols (47 real)
#define AST  260      // f32 LDS row stride (256 + 4)
#define RST  13       // s_red inner stride (12 + 1)

typedef short  bf16x8 __attribute__((ext_vector_type(8)));
typedef float  f32x4  __attribute__((ext_vector_type(4)));

__device__ __forceinline__ short f2bf(float f) {
    union { float f; unsigned u; } x; x.f = f;
    const unsigned r = x.u + 0x7fffu + ((x.u >> 16) & 1u);  // RNE
    return (short)(r >> 16);
}
__device__ __forceinline__ float bf2f(short s) {
    union { unsigned u; float f; } x; x.u = ((unsigned)(unsigned short)s) << 16;
    return x.f;
}
__device__ __forceinline__ float softplus_f(float x) {
    return (x > 20.f) ? x : log1pf(expf(x));
}

// ---------------------------------------------------------------------------
// Kernel 0: pack weights into pre-swizzled MFMA fragment order:
// Wpk[hl][chunk][nt][lane][8], element = W[k][j] hi/lo bf16 where
// k = chunk*32 + (lane>>4)*8 + e, j = nt*16 + (lane&15).
// A wave's B-fragment load is then one fully coalesced 1 KB read.
// ---------------------------------------------------------------------------
__global__ __launch_bounds__(256) void pack_kernel(
    const float* __restrict__ Wmix,
    const float* __restrict__ Wmean,
    const float* __restrict__ Wscale,
    short* __restrict__ Wpk)
{
    const int e  = blockIdx.x * 256 + threadIdx.x;   // 0 .. 98303
    const int hl = e / 49152;
    int r        = e - hl * 49152;
    const int chunk = r / 1536;  r -= chunk * 1536;
    const int nt    = r / 512;   r -= nt * 512;
    const int l     = r >> 3;
    const int ee    = r & 7;

    const int k = chunk * 32 + ((l >> 4) << 3) + ee;
    const int j = nt * 16 + (l & 15);

    float v;
    if (j < 5)       v = Wmix[k * 5 + j];
    else if (j < 17) v = Wmean[k * 12 + (j - 5)];
    else if (j < 47) v = Wscale[k * 30 + (j - 17)];
    else             v = 0.f;

    const short h = f2bf(v);
    Wpk[e] = hl ? f2bf(v - bf2f(h)) : h;
}

// ---------------------------------------------------------------------------
// Kernel 1: head GEMM. grid (256 row-blocks, 4 k-splits) x 256 threads.
// Block: stage 16 rows x 256 k of rep as f32 in LDS (plain float4 copy),
// each wave = one 64-k quarter (2 MFMA k-chunks), split-bf16 at read time.
// Cross-wave LDS reduce, cooperative coalesced store to gemmout[kz][j][b].
// ---------------------------------------------------------------------------
__global__ __launch_bounds__(256) void gemm_kernel(
    const float* __restrict__ rep,
    const short* __restrict__ Wpk,
    float* __restrict__ gemmout)
{
    __shared__ float s_a[GR][AST];          // 16.6 KB
    __shared__ float s_red[4][64][RST];     // 13.3 KB

    const int t  = threadIdx.x;
    const int w  = t >> 6;
    const int l  = t & 63;
    const int lm = l & 15;
    const int lk = (l >> 4) * 8;
    const int b0 = blockIdx.x * GR;
    const int k0 = blockIdx.y * BK;

    // ---- stage: 16 rows x 256 f32, 4 coalesced float4 per thread ----
#pragma unroll
    for (int i = 0; i < 4; ++i) {
        const int s   = i * 256 + t;
        const int row = s >> 6;          // 64 float4 per row
        const int c4  = s & 63;
        *(f32x4*)(&s_a[row][c4 * 4]) =
            *(const f32x4*)(rep + (size_t)(b0 + row) * DD + k0 + c4 * 4);
    }
    __syncthreads();

    // ---- MFMA over this wave's 64-k quarter ----
    f32x4 acc[3] = {f32x4{0,0,0,0}, f32x4{0,0,0,0}, f32x4{0,0,0,0}};

#pragma unroll
    for (int kt = 0; kt < 2; ++kt) {
        const int kof = w * 64 + kt * 32 + lk;
        const f32x4 a0 = *(const f32x4*)(&s_a[lm][kof]);
        const f32x4 a1 = *(const f32x4*)(&s_a[lm][kof + 4]);

        bf16x8 ah, al;
#pragma unroll
        for (int u = 0; u < 4; ++u) {
            const short h0 = f2bf(a0[u]);
            const short h1 = f2bf(a1[u]);
            ah[u]     = h0;
            ah[u + 4] = h1;
            al[u]     = f2bf(a0[u] - bf2f(h0));
            al[u + 4] = f2bf(a1[u] - bf2f(h1));
        }

        const int chunk = blockIdx.y * 8 + w * 2 + kt;   // global 32-k chunk
#pragma unroll
        for (int nt = 0; nt < 3; ++nt) {
            const bf16x8 bh = *(const bf16x8*)(Wpk + (((size_t)chunk * 3 + nt) * 64 + l) * 8);
            const bf16x8 bl = *(const bf16x8*)(Wpk + ((((size_t)(32 + chunk)) * 3 + nt) * 64 + l) * 8);
            acc[nt] = __builtin_amdgcn_mfma_f32_16x16x32_bf16(ah, bh, acc[nt], 0, 0, 0);
            acc[nt] = __builtin_amdgcn_mfma_f32_16x16x32_bf16(ah, bl, acc[nt], 0, 0, 0);
            acc[nt] = __builtin_amdgcn_mfma_f32_16x16x32_bf16(al, bh, acc[nt], 0, 0, 0);
        }
    }

    // ---- cross-wave reduce via LDS ----
#pragma unroll
    for (int nt = 0; nt < 3; ++nt)
#pragma unroll
        for (int r = 0; r < 4; ++r)
            s_red[w][l][nt * 4 + r] = acc[nt][r];
    __syncthreads();

    // cooperative: 752 = 16 b x 47 j elements, coalesced store (b fastest)
    // C layout [m89]: col(=j) = lane&15, row(=b_loc) = (lane>>4)*4 + reg
    for (int e = t; e < GR * 47; e += 256) {
        const int b_loc = e & 15;
        const int j     = e >> 4;
        const int lane  = ((b_loc >> 2) << 4) | (j & 15);
        const int reg   = ((j >> 4) << 2) | (b_loc & 3);
        const float s = s_red[0][lane][reg] + s_red[1][lane][reg]
                      + s_red[2][lane][reg] + s_red[3][lane][reg];
        gemmout[((size_t)blockIdx.y * NC + j) * BB + b0 + b_loc] = s;
    }
}

// ---------------------------------------------------------------------------
// Kernel 2: tail. One thread per batch row, all loads/stores coalesced
// (gemmout and par are [j][b] SoA). Softmax, softplus Cholesky, L + par.
// ---------------------------------------------------------------------------
__global__ __launch_bounds__(256) void tail_kernel(
    const float* __restrict__ gemmout,
    const float* __restrict__ bmix,
    const float* __restrict__ bmean,
    const float* __restrict__ bscale,
    float* __restrict__ Lout,
    float* __restrict__ par)
{
    const int b = blockIdx.x * 256 + threadIdx.x;

    float v[47];
#pragma unroll
    for (int j = 0; j < 47; ++j) {
        float s = 0.f;
#pragma unroll
        for (int kz = 0; kz < KSPL; ++kz)
            s += gemmout[((size_t)kz * NC + j) * BB + b];
        v[j] = s;
    }

    // softmax over 5 logits
    float logits[KK];
#pragma unroll
    for (int k = 0; k < KK; ++k) logits[k] = v[k] + bmix[k];
    float mx = logits[0];
#pragma unroll
    for (int k = 1; k < KK; ++k) mx = fmaxf(mx, logits[k]);
    float e[KK]; float s = 0.f;
#pragma unroll
    for (int k = 0; k < KK; ++k) { e[k] = expf(logits[k] - mx); s += e[k]; }
    const float inv_s = 1.f / s;

    float means[12];
#pragma unroll
    for (int j = 0; j < 12; ++j) means[j] = v[5 + j] + bmean[j];

#pragma unroll
    for (int k = 0; k < KK; ++k) {
        const float s0 = v[17 + k * 6 + 0] + bscale[k * 6 + 0];
        const float s1 = v[17 + k * 6 + 1] + bscale[k * 6 + 1];
        const float s2 = v[17 + k * 6 + 2] + bscale[k * 6 + 2];
        const float s3 = v[17 + k * 6 + 3] + bscale[k * 6 + 3];
        const float s4 = v[17 + k * 6 + 4] + bscale[k * 6 + 4];
        const float s5 = v[17 + k * 6 + 5] + bscale[k * 6 + 5];

        const float L00 = softplus_f(s0);
        const float L10 = s1;
        const float L11 = softplus_f(s2);
        const float L20 = s3;
        const float L21 = s4;
        const float L22 = softplus_f(s5);

        const float m0 = (k == 0) ? 0.f : means[(k - 1) * 3 + 0];
        const float m1 = (k == 0) ? 0.f : means[(k - 1) * 3 + 1];
        const float m2 = (k == 0) ? 0.f : means[(k - 1) * 3 + 2];

        const float r00 = 1.f / L00;
        const float r11 = 1.f / L11;
        const float r22 = 1.f / L22;
        const float wgt = e[k] * inv_s;
        const float a   = wgt * r00 * r11 * r22 * INV_2PI_POW15;

        float* Lo = Lout + ((size_t)b * KK + k) * 9;
        Lo[0] = L00; Lo[1] = 0.f; Lo[2] = 0.f;
        Lo[3] = L10; Lo[4] = L11; Lo[5] = 0.f;
        Lo[6] = L20; Lo[7] = L21; Lo[8] = L22;

        const int pj = k * 10;
        par[(pj + 0) * BB + b] = m0;
        par[(pj + 1) * BB + b] = m1;
        par[(pj + 2) * BB + b] = m2;
        par[(pj + 3) * BB + b] = r00;
        par[(pj + 4) * BB + b] = L10;
        par[(pj + 5) * BB + b] = r11;
        par[(pj + 6) * BB + b] = L20;
        par[(pj + 7) * BB + b] = L21;
        par[(pj + 8) * BB + b] = r22;
        par[(pj + 9) * BB + b] = a;
    }
}

// ---------------------------------------------------------------------------
// Kernel 3: per-(p,b) mixture density (memory-bound, at HBM floor).
// out[p*B + b] = sum_k a_k * exp(-0.5 * |L^-1 (x - mu)|^2)
// ---------------------------------------------------------------------------
__global__ __launch_bounds__(256) void eval_kernel(
    const float* __restrict__ dxyz,
    const float* __restrict__ par,
    float* __restrict__ out)
{
    const int b = blockIdx.x * 256 + threadIdx.x;

    float m0[KK], m1[KK], m2[KK], r00[KK], l10[KK], r11[KK], l20[KK], l21[KK], r22[KK], am[KK];
#pragma unroll
    for (int k = 0; k < KK; ++k) {
        const int pj = k * 10;
        m0[k]  = par[(pj + 0) * BB + b];
        m1[k]  = par[(pj + 1) * BB + b];
        m2[k]  = par[(pj + 2) * BB + b];
        r00[k] = par[(pj + 3) * BB + b];
        l10[k] = par[(pj + 4) * BB + b];
        r11[k] = par[(pj + 5) * BB + b];
        l20[k] = par[(pj + 6) * BB + b];
        l21[k] = par[(pj + 7) * BB + b];
        r22[k] = par[(pj + 8) * BB + b];
        am[k]  = par[(pj + 9) * BB + b];
    }

    const int p0 = blockIdx.y * PTS_PER_THREAD;
#pragma unroll 3
    for (int i = 0; i < PTS_PER_THREAD; ++i) {
        const int p = p0 + i;
        const size_t idx = (size_t)p * BB + b;
        const float* xv = dxyz + idx * 3;
        const float x0 = xv[0];
        const float x1 = xv[1];
        const float x2 = xv[2];

        float res = 0.f;
#pragma unroll
        for (int k = 0; k < KK; ++k) {
            const float d0 = x0 - m0[k];
            const float d1 = x1 - m1[k];
            const float d2 = x2 - m2[k];
            const float z0 = d0 * r00[k];
            const float z1 = fmaf(-l10[k], z0, d1) * r11[k];
            const float z2 = fmaf(-l21[k], z1, fmaf(-l20[k], z0, d2)) * r22[k];
            const float q  = fmaf(z2, z2, fmaf(z1, z1, z0 * z0));
            res = fmaf(am[k], __expf(-0.5f * q), res);
        }
        out[idx] = res;
    }
}

extern "C" void kernel_launch(void* const* d_in, const int* in_sizes, int n_in,
                              void* d_out, int out_size, void* d_ws, size_t ws_size,
                              hipStream_t stream) {
    const float* rep    = (const float*)d_in[0];
    const float* dxyz   = (const float*)d_in[1];
    const float* Wmix   = (const float*)d_in[2];
    const float* bmix   = (const float*)d_in[3];
    const float* Wmean  = (const float*)d_in[4];
    const float* bmean  = (const float*)d_in[5];
    const float* Wscale = (const float*)d_in[6];
    const float* bscale = (const float*)d_in[7];

    float* out  = (float*)d_out;
    float* Lout = out + (size_t)BB * PP;          // second tuple output

    float* par     = (float*)d_ws;                         // 50*B f32      (819 KB)
    float* gemmout = par + 50 * BB;                        // 4*48*B f32    (3.15 MB)
    short* Wpk     = (short*)(gemmout + (size_t)KSPL * NC * BB);  // 98304 bf16 (196 KB)

    pack_kernel<<<384, 256, 0, stream>>>(Wmix, Wmean, Wscale, Wpk);

    gemm_kernel<<<dim3(BB / GR, KSPL), 256, 0, stream>>>(rep, Wpk, gemmout);

    tail_kernel<<<BB / 256, 256, 0, stream>>>(gemmout, bmix, bmean, bscale, Lout, par);

    eval_kernel<<<dim3(BB / 256, PP / PTS_PER_THREAD), 256, 0, stream>>>(dxyz, par, out);
}

// Round 6
// 41.337 us; speedup vs baseline: 1.1400x; 1.1400x over previous
//
#include <hip/hip_runtime.h>
#include <math.h>

#define BB 4096
#define DD 1024
#define KK 5
#define PP 1323
#define PTS_PER_THREAD 21   // 1323 = 63 * 21

// (2*pi)^(-3/2)
#define INV_2PI_POW15 0.06349363593424097f

// ---- head GEMM config ----
#define KSPL 4        // k-split (grid.y)
#define BK   256      // K per block
#define GR   16       // rows per block
#define NC   48       // padded output cols (47 real)
#define AST  260      // f32 LDS row stride (256 + 4)
#define RST  13       // s_red inner stride (12 + 1)

typedef short  bf16x8 __attribute__((ext_vector_type(8)));
typedef float  f32x4  __attribute__((ext_vector_type(4)));

__device__ __forceinline__ short f2bf(float f) {
    union { float f; unsigned u; } x; x.f = f;
    const unsigned r = x.u + 0x7fffu + ((x.u >> 16) & 1u);  // RNE
    return (short)(r >> 16);
}
__device__ __forceinline__ float bf2f(short s) {
    union { unsigned u; float f; } x; x.u = ((unsigned)(unsigned short)s) << 16;
    return x.f;
}
__device__ __forceinline__ float softplus_f(float x) {
    return (x > 20.f) ? x : log1pf(expf(x));
}

// ---------------------------------------------------------------------------
// Kernel 0: pack weights into pre-swizzled MFMA fragment order:
// Wpk[hl][chunk][nt][lane][8], element = W[k][j] hi/lo bf16 where
// k = chunk*32 + (lane>>4)*8 + e, j = nt*16 + (lane&15).
// ---------------------------------------------------------------------------
__global__ __launch_bounds__(256) void pack_kernel(
    const float* __restrict__ Wmix,
    const float* __restrict__ Wmean,
    const float* __restrict__ Wscale,
    short* __restrict__ Wpk)
{
    const int e  = blockIdx.x * 256 + threadIdx.x;   // 0 .. 98303
    const int hl = e / 49152;
    int r        = e - hl * 49152;
    const int chunk = r / 1536;  r -= chunk * 1536;
    const int nt    = r / 512;   r -= nt * 512;
    const int l     = r >> 3;
    const int ee    = r & 7;

    const int k = chunk * 32 + ((l >> 4) << 3) + ee;
    const int j = nt * 16 + (l & 15);

    float v;
    if (j < 5)       v = Wmix[k * 5 + j];
    else if (j < 17) v = Wmean[k * 12 + (j - 5)];
    else if (j < 47) v = Wscale[k * 30 + (j - 17)];
    else             v = 0.f;

    const short h = f2bf(v);
    Wpk[e] = hl ? f2bf(v - bf2f(h)) : h;
}

// ---------------------------------------------------------------------------
// Kernel 1: head GEMM. grid (256 row-blocks, 4 k-splits) x 256 threads.
// Stage 16x256 rep f32 in LDS; wave = 64-k quarter; split-bf16 at read time;
// cross-wave LDS reduce; cooperative coalesced store to gemmout[kz][j][b].
// ---------------------------------------------------------------------------
__global__ __launch_bounds__(256) void gemm_kernel(
    const float* __restrict__ rep,
    const short* __restrict__ Wpk,
    float* __restrict__ gemmout)
{
    __shared__ float s_a[GR][AST];          // 16.6 KB
    __shared__ float s_red[4][64][RST];     // 13.3 KB

    const int t  = threadIdx.x;
    const int w  = t >> 6;
    const int l  = t & 63;
    const int lm = l & 15;
    const int lk = (l >> 4) * 8;
    const int b0 = blockIdx.x * GR;
    const int k0 = blockIdx.y * BK;

#pragma unroll
    for (int i = 0; i < 4; ++i) {
        const int s   = i * 256 + t;
        const int row = s >> 6;
        const int c4  = s & 63;
        *(f32x4*)(&s_a[row][c4 * 4]) =
            *(const f32x4*)(rep + (size_t)(b0 + row) * DD + k0 + c4 * 4);
    }
    __syncthreads();

    f32x4 acc[3] = {f32x4{0,0,0,0}, f32x4{0,0,0,0}, f32x4{0,0,0,0}};

#pragma unroll
    for (int kt = 0; kt < 2; ++kt) {
        const int kof = w * 64 + kt * 32 + lk;
        const f32x4 a0 = *(const f32x4*)(&s_a[lm][kof]);
        const f32x4 a1 = *(const f32x4*)(&s_a[lm][kof + 4]);

        bf16x8 ah, al;
#pragma unroll
        for (int u = 0; u < 4; ++u) {
            const short h0 = f2bf(a0[u]);
            const short h1 = f2bf(a1[u]);
            ah[u]     = h0;
            ah[u + 4] = h1;
            al[u]     = f2bf(a0[u] - bf2f(h0));
            al[u + 4] = f2bf(a1[u] - bf2f(h1));
        }

        const int chunk = blockIdx.y * 8 + w * 2 + kt;
#pragma unroll
        for (int nt = 0; nt < 3; ++nt) {
            const bf16x8 bh = *(const bf16x8*)(Wpk + (((size_t)chunk * 3 + nt) * 64 + l) * 8);
            const bf16x8 bl = *(const bf16x8*)(Wpk + ((((size_t)(32 + chunk)) * 3 + nt) * 64 + l) * 8);
            acc[nt] = __builtin_amdgcn_mfma_f32_16x16x32_bf16(ah, bh, acc[nt], 0, 0, 0);
            acc[nt] = __builtin_amdgcn_mfma_f32_16x16x32_bf16(ah, bl, acc[nt], 0, 0, 0);
            acc[nt] = __builtin_amdgcn_mfma_f32_16x16x32_bf16(al, bh, acc[nt], 0, 0, 0);
        }
    }

#pragma unroll
    for (int nt = 0; nt < 3; ++nt)
#pragma unroll
        for (int r = 0; r < 4; ++r)
            s_red[w][l][nt * 4 + r] = acc[nt][r];
    __syncthreads();

    // cooperative coalesced store (b fastest); C layout [m89]
    for (int e = t; e < GR * 47; e += 256) {
        const int b_loc = e & 15;
        const int j     = e >> 4;
        const int lane  = ((b_loc >> 2) << 4) | (j & 15);
        const int reg   = ((j >> 4) << 2) | (b_loc & 3);
        const float s = s_red[0][lane][reg] + s_red[1][lane][reg]
                      + s_red[2][lane][reg] + s_red[3][lane][reg];
        gemmout[((size_t)blockIdx.y * NC + j) * BB + b0 + b_loc] = s;
    }
}

// ---------------------------------------------------------------------------
// Kernel 2: tail over (b,k) pairs. 20480 threads (t = k*BB + b), 80 blocks.
// All gemmout loads coalesced (lane-consecutive b, fixed k). Each thread
// redundantly computes the 5-logit softmax, then its own component's
// Cholesky + L write + par write.
// ---------------------------------------------------------------------------
__global__ __launch_bounds__(256) void tail_kernel(
    const float* __restrict__ gemmout,
    const float* __restrict__ bmix,
    const float* __restrict__ bmean,
    const float* __restrict__ bscale,
    float* __restrict__ Lout,
    float* __restrict__ par)
{
    const int t = blockIdx.x * 256 + threadIdx.x;   // 0 .. 20479
    const int k = t >> 12;                          // component 0..4
    const int b = t & (BB - 1);                     // batch row

    // ---- logits (all 5, for softmax): 20 coalesced loads ----
    float logits[KK];
#pragma unroll
    for (int kk = 0; kk < KK; ++kk) {
        float s = 0.f;
#pragma unroll
        for (int kz = 0; kz < KSPL; ++kz)
            s += gemmout[((size_t)kz * NC + kk) * BB + b];
        logits[kk] = s + bmix[kk];
    }

    // ---- own means (3): mask k==0 ----
    const int jm = 5 + (k > 0 ? (k - 1) * 3 : 0);
    float m[3];
#pragma unroll
    for (int c = 0; c < 3; ++c) {
        float s = 0.f;
#pragma unroll
        for (int kz = 0; kz < KSPL; ++kz)
            s += gemmout[((size_t)kz * NC + jm + c) * BB + b];
        m[c] = (k > 0) ? (s + bmean[(k - 1) * 3 + c]) : 0.f;
    }

    // ---- own scales (6) ----
    float sc[6];
#pragma unroll
    for (int c = 0; c < 6; ++c) {
        float s = 0.f;
#pragma unroll
        for (int kz = 0; kz < KSPL; ++kz)
            s += gemmout[((size_t)kz * NC + 17 + k * 6 + c) * BB + b];
        sc[c] = s + bscale[k * 6 + c];
    }

    // softmax weight for this k
    float mx = logits[0];
#pragma unroll
    for (int kk = 1; kk < KK; ++kk) mx = fmaxf(mx, logits[kk]);
    float den = 0.f;
#pragma unroll
    for (int kk = 0; kk < KK; ++kk) den += expf(logits[kk] - mx);
    const float w = expf(logits[k] - mx) / den;

    const float L00 = softplus_f(sc[0]);
    const float L10 = sc[1];
    const float L11 = softplus_f(sc[2]);
    const float L20 = sc[3];
    const float L21 = sc[4];
    const float L22 = softplus_f(sc[5]);

    const float r00 = 1.f / L00;
    const float r11 = 1.f / L11;
    const float r22 = 1.f / L22;
    const float a   = w * r00 * r11 * r22 * INV_2PI_POW15;

    float* Lo = Lout + ((size_t)b * KK + k) * 9;
    Lo[0] = L00; Lo[1] = 0.f; Lo[2] = 0.f;
    Lo[3] = L10; Lo[4] = L11; Lo[5] = 0.f;
    Lo[6] = L20; Lo[7] = L21; Lo[8] = L22;

    const int pj = k * 10;
    par[(pj + 0) * BB + b] = m[0];
    par[(pj + 1) * BB + b] = m[1];
    par[(pj + 2) * BB + b] = m[2];
    par[(pj + 3) * BB + b] = r00;
    par[(pj + 4) * BB + b] = L10;
    par[(pj + 5) * BB + b] = r11;
    par[(pj + 6) * BB + b] = L20;
    par[(pj + 7) * BB + b] = L21;
    par[(pj + 8) * BB + b] = r22;
    par[(pj + 9) * BB + b] = a;
}

// ---------------------------------------------------------------------------
// Kernel 3: per-(p,b) mixture density (memory-bound, at HBM floor).
// ---------------------------------------------------------------------------
__global__ __launch_bounds__(256) void eval_kernel(
    const float* __restrict__ dxyz,
    const float* __restrict__ par,
    float* __restrict__ out)
{
    const int b = blockIdx.x * 256 + threadIdx.x;

    float m0[KK], m1[KK], m2[KK], r00[KK], l10[KK], r11[KK], l20[KK], l21[KK], r22[KK], am[KK];
#pragma unroll
    for (int k = 0; k < KK; ++k) {
        const int pj = k * 10;
        m0[k]  = par[(pj + 0) * BB + b];
        m1[k]  = par[(pj + 1) * BB + b];
        m2[k]  = par[(pj + 2) * BB + b];
        r00[k] = par[(pj + 3) * BB + b];
        l10[k] = par[(pj + 4) * BB + b];
        r11[k] = par[(pj + 5) * BB + b];
        l20[k] = par[(pj + 6) * BB + b];
        l21[k] = par[(pj + 7) * BB + b];
        r22[k] = par[(pj + 8) * BB + b];
        am[k]  = par[(pj + 9) * BB + b];
    }

    const int p0 = blockIdx.y * PTS_PER_THREAD;
#pragma unroll 3
    for (int i = 0; i < PTS_PER_THREAD; ++i) {
        const int p = p0 + i;
        const size_t idx = (size_t)p * BB + b;
        const float* xv = dxyz + idx * 3;
        const float x0 = xv[0];
        const float x1 = xv[1];
        const float x2 = xv[2];

        float res = 0.f;
#pragma unroll
        for (int k = 0; k < KK; ++k) {
            const float d0 = x0 - m0[k];
            const float d1 = x1 - m1[k];
            const float d2 = x2 - m2[k];
            const float z0 = d0 * r00[k];
            const float z1 = fmaf(-l10[k], z0, d1) * r11[k];
            const float z2 = fmaf(-l21[k], z1, fmaf(-l20[k], z0, d2)) * r22[k];
            const float q  = fmaf(z2, z2, fmaf(z1, z1, z0 * z0));
            res = fmaf(am[k], __expf(-0.5f * q), res);
        }
        out[idx] = res;
    }
}

extern "C" void kernel_launch(void* const* d_in, const int* in_sizes, int n_in,
                              void* d_out, int out_size, void* d_ws, size_t ws_size,
                              hipStream_t stream) {
    const float* rep    = (const float*)d_in[0];
    const float* dxyz   = (const float*)d_in[1];
    const float* Wmix   = (const float*)d_in[2];
    const float* bmix   = (const float*)d_in[3];
    const float* Wmean  = (const float*)d_in[4];
    const float* bmean  = (const float*)d_in[5];
    const float* Wscale = (const float*)d_in[6];
    const float* bscale = (const float*)d_in[7];

    float* out  = (float*)d_out;
    float* Lout = out + (size_t)BB * PP;          // second tuple output

    float* par     = (float*)d_ws;                         // 50*B f32      (819 KB)
    float* gemmout = par + 50 * BB;                        // 4*48*B f32    (3.15 MB)
    short* Wpk     = (short*)(gemmout + (size_t)KSPL * NC * BB);  // 98304 bf16 (196 KB)

    pack_kernel<<<384, 256, 0, stream>>>(Wmix, Wmean, Wscale, Wpk);

    gemm_kernel<<<dim3(BB / GR, KSPL), 256, 0, stream>>>(rep, Wpk, gemmout);

    tail_kernel<<<80, 256, 0, stream>>>(gemmout, bmix, bmean, bscale, Lout, par);

    eval_kernel<<<dim3(BB / 256, PP / PTS_PER_THREAD), 256, 0, stream>>>(dxyz, par, out);
}

// Round 7
// 39.592 us; speedup vs baseline: 1.1903x; 1.0441x over previous
//
#include <hip/hip_runtime.h>
#include <math.h>

#define BB 4096
#define DD 1024
#define KK 5
#define PP 1323
#define PTS_PER_THREAD 21   // 1323 = 63 * 21

// (2*pi)^(-3/2)
#define INV_2PI_POW15 0.06349363593424097f

// ---- fused head config ----
#define GR   16       // rows per block -> 256 blocks (1 per CU)
#define NC   48       // padded output cols (47 real)
#define AST  1028     // f32 LDS row stride (1024 + 4 -> bank spread)
#define RST  13       // s_red inner stride
#define CSTR 49       // s_c inner stride

typedef short  bf16x8 __attribute__((ext_vector_type(8)));
typedef float  f32x4  __attribute__((ext_vector_type(4)));

__device__ __forceinline__ short f2bf(float f) {
    union { float f; unsigned u; } x; x.f = f;
    const unsigned r = x.u + 0x7fffu + ((x.u >> 16) & 1u);  // RNE
    return (short)(r >> 16);
}
__device__ __forceinline__ float bf2f(short s) {
    union { unsigned u; float f; } x; x.u = ((unsigned)(unsigned short)s) << 16;
    return x.f;
}
__device__ __forceinline__ float softplus_f(float x) {
    return (x > 20.f) ? x : log1pf(expf(x));
}

// ---------------------------------------------------------------------------
// Kernel 0: pack weights into pre-swizzled MFMA fragment order:
// Wpk[hl][chunk][nt][lane][8], element = W[k][j] hi/lo bf16 where
// k = chunk*32 + (lane>>4)*8 + e, j = nt*16 + (lane&15).
// A wave's B-fragment load is one fully coalesced 1 KB read.
// ---------------------------------------------------------------------------
__global__ __launch_bounds__(256) void pack_kernel(
    const float* __restrict__ Wmix,
    const float* __restrict__ Wmean,
    const float* __restrict__ Wscale,
    short* __restrict__ Wpk)
{
    const int e  = blockIdx.x * 256 + threadIdx.x;   // 0 .. 98303
    const int hl = e / 49152;
    int r        = e - hl * 49152;
    const int chunk = r / 1536;  r -= chunk * 1536;
    const int nt    = r / 512;   r -= nt * 512;
    const int l     = r >> 3;
    const int ee    = r & 7;

    const int k = chunk * 32 + ((l >> 4) << 3) + ee;
    const int j = nt * 16 + (l & 15);

    float v;
    if (j < 5)       v = Wmix[k * 5 + j];
    else if (j < 17) v = Wmean[k * 12 + (j - 5)];
    else if (j < 47) v = Wscale[k * 30 + (j - 17)];
    else             v = 0.f;

    const short h = f2bf(v);
    Wpk[e] = hl ? f2bf(v - bf2f(h)) : h;
}

// ---------------------------------------------------------------------------
// Kernel 1: fused head. 256 blocks (1/CU) x 16 rows, full K=1024 per block.
// Stage 16x1024 rep f32 in LDS; wave w = k-range [256w, 256w+256) as 8 MFMA
// chunks (split-bf16 at fragment read, 72 MFMAs/wave); cross-wave LDS
// reduce; 80-thread (b,k) tail from LDS writes L and SoA par directly.
// ---------------------------------------------------------------------------
__global__ __launch_bounds__(256) void head_fused_kernel(
    const float* __restrict__ rep,
    const short* __restrict__ Wpk,
    const float* __restrict__ bmix,
    const float* __restrict__ bmean,
    const float* __restrict__ bscale,
    float* __restrict__ Lout,
    float* __restrict__ par)
{
    __shared__ float s_a[GR][AST];          // 65.8 KB
    __shared__ float s_red[4][64][RST];     // 13.3 KB
    __shared__ float s_c[GR][CSTR];         // 3.1 KB

    const int t  = threadIdx.x;
    const int w  = t >> 6;
    const int l  = t & 63;
    const int lm = l & 15;
    const int lk = (l >> 4) * 8;
    const int b0 = blockIdx.x * GR;

    // ---- stage 16 rows x 1024 f32 (16 coalesced float4 per thread) ----
#pragma unroll
    for (int i = 0; i < 16; ++i) {
        const int s   = i * 256 + t;
        const int row = s >> 8;          // 256 float4 per row
        const int c4  = s & 255;
        *(f32x4*)(&s_a[row][c4 * 4]) =
            *(const f32x4*)(rep + (size_t)(b0 + row) * DD + c4 * 4);
    }
    __syncthreads();

    // ---- MFMA over this wave's 256-k quarter ----
    f32x4 acc[3] = {f32x4{0,0,0,0}, f32x4{0,0,0,0}, f32x4{0,0,0,0}};

#pragma unroll
    for (int kt = 0; kt < 8; ++kt) {
        const int kof = w * 256 + kt * 32 + lk;
        const f32x4 a0 = *(const f32x4*)(&s_a[lm][kof]);
        const f32x4 a1 = *(const f32x4*)(&s_a[lm][kof + 4]);

        bf16x8 ah, al;
#pragma unroll
        for (int u = 0; u < 4; ++u) {
            const short h0 = f2bf(a0[u]);
            const short h1 = f2bf(a1[u]);
            ah[u]     = h0;
            ah[u + 4] = h1;
            al[u]     = f2bf(a0[u] - bf2f(h0));
            al[u + 4] = f2bf(a1[u] - bf2f(h1));
        }

        const int chunk = w * 8 + kt;    // global 32-k chunk 0..31
#pragma unroll
        for (int nt = 0; nt < 3; ++nt) {
            const bf16x8 bh = *(const bf16x8*)(Wpk + (((size_t)chunk * 3 + nt) * 64 + l) * 8);
            const bf16x8 bl = *(const bf16x8*)(Wpk + ((((size_t)(32 + chunk)) * 3 + nt) * 64 + l) * 8);
            acc[nt] = __builtin_amdgcn_mfma_f32_16x16x32_bf16(ah, bh, acc[nt], 0, 0, 0);
            acc[nt] = __builtin_amdgcn_mfma_f32_16x16x32_bf16(ah, bl, acc[nt], 0, 0, 0);
            acc[nt] = __builtin_amdgcn_mfma_f32_16x16x32_bf16(al, bh, acc[nt], 0, 0, 0);
        }
    }

    // ---- cross-wave reduce via LDS ----
#pragma unroll
    for (int nt = 0; nt < 3; ++nt)
#pragma unroll
        for (int r = 0; r < 4; ++r)
            s_red[w][l][nt * 4 + r] = acc[nt][r];
    __syncthreads();

    // cooperative sum into s_c[b_loc][j]; C layout [m89]:
    // col(=j) = lane&15, row(=b_loc) = (lane>>4)*4 + reg
    for (int e = t; e < GR * 47; e += 256) {
        const int b_loc = e & 15;
        const int j     = e >> 4;
        const int lane  = ((b_loc >> 2) << 4) | (j & 15);
        const int reg   = ((j >> 4) << 2) | (b_loc & 3);
        s_c[b_loc][j] = s_red[0][lane][reg] + s_red[1][lane][reg]
                      + s_red[2][lane][reg] + s_red[3][lane][reg];
    }
    __syncthreads();

    // ---- tail: 80 threads = 16 b x 5 k ----
    if (t < GR * KK) {
        const int k     = t >> 4;
        const int b_loc = t & 15;
        const int b     = b0 + b_loc;

        float logits[KK];
#pragma unroll
        for (int kk = 0; kk < KK; ++kk) logits[kk] = s_c[b_loc][kk] + bmix[kk];

        float m[3];
#pragma unroll
        for (int c = 0; c < 3; ++c)
            m[c] = (k > 0) ? (s_c[b_loc][5 + (k - 1) * 3 + c] + bmean[(k - 1) * 3 + c]) : 0.f;

        float sc[6];
#pragma unroll
        for (int c = 0; c < 6; ++c)
            sc[c] = s_c[b_loc][17 + k * 6 + c] + bscale[k * 6 + c];

        float mx = logits[0];
#pragma unroll
        for (int kk = 1; kk < KK; ++kk) mx = fmaxf(mx, logits[kk]);
        float den = 0.f;
#pragma unroll
        for (int kk = 0; kk < KK; ++kk) den += expf(logits[kk] - mx);
        const float wgt = expf(logits[k] - mx) / den;

        const float L00 = softplus_f(sc[0]);
        const float L10 = sc[1];
        const float L11 = softplus_f(sc[2]);
        const float L20 = sc[3];
        const float L21 = sc[4];
        const float L22 = softplus_f(sc[5]);

        const float r00 = 1.f / L00;
        const float r11 = 1.f / L11;
        const float r22 = 1.f / L22;
        const float a   = wgt * r00 * r11 * r22 * INV_2PI_POW15;

        float* Lo = Lout + ((size_t)b * KK + k) * 9;
        Lo[0] = L00; Lo[1] = 0.f; Lo[2] = 0.f;
        Lo[3] = L10; Lo[4] = L11; Lo[5] = 0.f;
        Lo[6] = L20; Lo[7] = L21; Lo[8] = L22;

        const int pj = k * 10;
        par[(pj + 0) * BB + b] = m[0];
        par[(pj + 1) * BB + b] = m[1];
        par[(pj + 2) * BB + b] = m[2];
        par[(pj + 3) * BB + b] = r00;
        par[(pj + 4) * BB + b] = L10;
        par[(pj + 5) * BB + b] = r11;
        par[(pj + 6) * BB + b] = L20;
        par[(pj + 7) * BB + b] = L21;
        par[(pj + 8) * BB + b] = r22;
        par[(pj + 9) * BB + b] = a;
    }
}

// ---------------------------------------------------------------------------
// Kernel 2: per-(p,b) mixture density (memory-bound, at HBM floor).
// out[p*B + b] = sum_k a_k * exp(-0.5 * |L^-1 (x - mu)|^2)
// ---------------------------------------------------------------------------
__global__ __launch_bounds__(256) void eval_kernel(
    const float* __restrict__ dxyz,
    const float* __restrict__ par,
    float* __restrict__ out)
{
    const int b = blockIdx.x * 256 + threadIdx.x;

    float m0[KK], m1[KK], m2[KK], r00[KK], l10[KK], r11[KK], l20[KK], l21[KK], r22[KK], am[KK];
#pragma unroll
    for (int k = 0; k < KK; ++k) {
        const int pj = k * 10;
        m0[k]  = par[(pj + 0) * BB + b];
        m1[k]  = par[(pj + 1) * BB + b];
        m2[k]  = par[(pj + 2) * BB + b];
        r00[k] = par[(pj + 3) * BB + b];
        l10[k] = par[(pj + 4) * BB + b];
        r11[k] = par[(pj + 5) * BB + b];
        l20[k] = par[(pj + 6) * BB + b];
        l21[k] = par[(pj + 7) * BB + b];
        r22[k] = par[(pj + 8) * BB + b];
        am[k]  = par[(pj + 9) * BB + b];
    }

    const int p0 = blockIdx.y * PTS_PER_THREAD;
#pragma unroll 3
    for (int i = 0; i < PTS_PER_THREAD; ++i) {
        const int p = p0 + i;
        const size_t idx = (size_t)p * BB + b;
        const float* xv = dxyz + idx * 3;
        const float x0 = xv[0];
        const float x1 = xv[1];
        const float x2 = xv[2];

        float res = 0.f;
#pragma unroll
        for (int k = 0; k < KK; ++k) {
            const float d0 = x0 - m0[k];
            const float d1 = x1 - m1[k];
            const float d2 = x2 - m2[k];
            const float z0 = d0 * r00[k];
            const float z1 = fmaf(-l10[k], z0, d1) * r11[k];
            const float z2 = fmaf(-l21[k], z1, fmaf(-l20[k], z0, d2)) * r22[k];
            const float q  = fmaf(z2, z2, fmaf(z1, z1, z0 * z0));
            res = fmaf(am[k], __expf(-0.5f * q), res);
        }
        out[idx] = res;
    }
}

extern "C" void kernel_launch(void* const* d_in, const int* in_sizes, int n_in,
                              void* d_out, int out_size, void* d_ws, size_t ws_size,
                              hipStream_t stream) {
    const float* rep    = (const float*)d_in[0];
    const float* dxyz   = (const float*)d_in[1];
    const float* Wmix   = (const float*)d_in[2];
    const float* bmix   = (const float*)d_in[3];
    const float* Wmean  = (const float*)d_in[4];
    const float* bmean  = (const float*)d_in[5];
    const float* Wscale = (const float*)d_in[6];
    const float* bscale = (const float*)d_in[7];

    float* out  = (float*)d_out;
    float* Lout = out + (size_t)BB * PP;          // second tuple output

    float* par = (float*)d_ws;                    // 50*B f32 (819 KB)
    short* Wpk = (short*)(par + 50 * BB);         // 98304 bf16 (196 KB)

    pack_kernel<<<384, 256, 0, stream>>>(Wmix, Wmean, Wscale, Wpk);

    head_fused_kernel<<<BB / GR, 256, 0, stream>>>(rep, Wpk, bmix, bmean, bscale, Lout, par);

    eval_kernel<<<dim3(BB / 256, PP / PTS_PER_THREAD), 256, 0, stream>>>(dxyz, par, out);
}

// Round 8
// 38.471 us; speedup vs baseline: 1.2250x; 1.0291x over previous
//
#include <hip/hip_runtime.h>
#include <math.h>

#define BB 4096
#define DD 1024
#define KK 5
#define PP 1323
#define PTS_PER_THREAD 21   // 1323 = 63 * 21

// (2*pi)^(-3/2)
#define INV_2PI_POW15 0.06349363593424097f

// ---- fused head config ----
#define GR   16       // rows per block -> 256 blocks (1 per CU)
#define NWV  16       // waves per block
#define NC   48       // padded output cols (47 real)
#define RST  13       // s_red inner stride (12 + 1)
#define CSTR 49       // s_c inner stride

typedef short  bf16x8 __attribute__((ext_vector_type(8)));
typedef float  f32x4  __attribute__((ext_vector_type(4)));

__device__ __forceinline__ short f2bf(float f) {
    union { float f; unsigned u; } x; x.f = f;
    const unsigned r = x.u + 0x7fffu + ((x.u >> 16) & 1u);  // RNE
    return (short)(r >> 16);
}
__device__ __forceinline__ float bf2f(short s) {
    union { unsigned u; float f; } x; x.u = ((unsigned)(unsigned short)s) << 16;
    return x.f;
}
__device__ __forceinline__ float softplus_f(float x) {
    return (x > 20.f) ? x : log1pf(expf(x));
}

// ---------------------------------------------------------------------------
// Kernel 0: pack weights into pre-swizzled MFMA fragment order:
// Wpk[hl][chunk][nt][lane][8], element = W[k][j] hi/lo bf16 where
// k = chunk*32 + (lane>>4)*8 + e, j = nt*16 + (lane&15).
// A wave's B-fragment load is one fully coalesced 1 KB read.
// ---------------------------------------------------------------------------
__global__ __launch_bounds__(256) void pack_kernel(
    const float* __restrict__ Wmix,
    const float* __restrict__ Wmean,
    const float* __restrict__ Wscale,
    short* __restrict__ Wpk)
{
    const int e  = blockIdx.x * 256 + threadIdx.x;   // 0 .. 98303
    const int hl = e / 49152;
    int r        = e - hl * 49152;
    const int chunk = r / 1536;  r -= chunk * 1536;
    const int nt    = r / 512;   r -= nt * 512;
    const int l     = r >> 3;
    const int ee    = r & 7;

    const int k = chunk * 32 + ((l >> 4) << 3) + ee;
    const int j = nt * 16 + (l & 15);

    float v;
    if (j < 5)       v = Wmix[k * 5 + j];
    else if (j < 17) v = Wmean[k * 12 + (j - 5)];
    else if (j < 47) v = Wscale[k * 30 + (j - 17)];
    else             v = 0.f;

    const short h = f2bf(v);
    Wpk[e] = hl ? f2bf(v - bf2f(h)) : h;
}

// ---------------------------------------------------------------------------
// Kernel 1: fused head, staging-free. 256 blocks x 1024 threads (16 waves).
// Wave w owns k in [64w, 64w+64) (2 MFMA chunks): A-fragments loaded
// DIRECTLY from global rep (L3-resident, every byte used), split-bf16 in
// register, B from pre-swizzled Wpk (coalesced, L2-resident). 16-deep
// cross-wave LDS reduce, then 80-thread (b,k) tail writes L and par.
// ---------------------------------------------------------------------------
__global__ __launch_bounds__(1024, 4) void head_fused_kernel(
    const float* __restrict__ rep,
    const short* __restrict__ Wpk,
    const float* __restrict__ bmix,
    const float* __restrict__ bmean,
    const float* __restrict__ bscale,
    float* __restrict__ Lout,
    float* __restrict__ par)
{
    __shared__ float s_red[NWV][64][RST];   // 53.2 KB
    __shared__ float s_c[GR][CSTR];         // 3.1 KB

    const int t  = threadIdx.x;
    const int w  = t >> 6;          // wave 0..15
    const int l  = t & 63;
    const int lm = l & 15;
    const int lk = (l >> 4) * 8;
    const int b0 = blockIdx.x * GR;

    f32x4 acc[3] = {f32x4{0,0,0,0}, f32x4{0,0,0,0}, f32x4{0,0,0,0}};

#pragma unroll
    for (int kt = 0; kt < 2; ++kt) {
        const int chunk = w * 2 + kt;        // global 32-k chunk 0..31
        const int kof   = chunk * 32 + lk;

        // A-fragment direct from global: row b0+lm, 8 consecutive k
        const float* arow = rep + (size_t)(b0 + lm) * DD + kof;
        const f32x4 a0 = *(const f32x4*)(arow);
        const f32x4 a1 = *(const f32x4*)(arow + 4);

        bf16x8 ah, al;
#pragma unroll
        for (int u = 0; u < 4; ++u) {
            const short h0 = f2bf(a0[u]);
            const short h1 = f2bf(a1[u]);
            ah[u]     = h0;
            ah[u + 4] = h1;
            al[u]     = f2bf(a0[u] - bf2f(h0));
            al[u + 4] = f2bf(a1[u] - bf2f(h1));
        }

#pragma unroll
        for (int nt = 0; nt < 3; ++nt) {
            const bf16x8 bh = *(const bf16x8*)(Wpk + (((size_t)chunk * 3 + nt) * 64 + l) * 8);
            const bf16x8 bl = *(const bf16x8*)(Wpk + ((((size_t)(32 + chunk)) * 3 + nt) * 64 + l) * 8);
            acc[nt] = __builtin_amdgcn_mfma_f32_16x16x32_bf16(ah, bh, acc[nt], 0, 0, 0);
            acc[nt] = __builtin_amdgcn_mfma_f32_16x16x32_bf16(ah, bl, acc[nt], 0, 0, 0);
            acc[nt] = __builtin_amdgcn_mfma_f32_16x16x32_bf16(al, bh, acc[nt], 0, 0, 0);
        }
    }

    // ---- cross-wave reduce via LDS (16 partials) ----
#pragma unroll
    for (int nt = 0; nt < 3; ++nt)
#pragma unroll
        for (int r = 0; r < 4; ++r)
            s_red[w][l][nt * 4 + r] = acc[nt][r];
    __syncthreads();

    // cooperative sum into s_c[b_loc][j]; C layout [m89]:
    // col(=j) = lane&15, row(=b_loc) = (lane>>4)*4 + reg
    if (t < GR * 47) {
        const int b_loc = t & 15;
        const int j     = t >> 4;
        const int lane  = ((b_loc >> 2) << 4) | (j & 15);
        const int reg   = ((j >> 4) << 2) | (b_loc & 3);
        float s = 0.f;
#pragma unroll
        for (int q = 0; q < NWV; ++q) s += s_red[q][lane][reg];
        s_c[b_loc][j] = s;
    }
    __syncthreads();

    // ---- tail: 80 threads = 16 b x 5 k ----
    if (t < GR * KK) {
        const int k     = t >> 4;
        const int b_loc = t & 15;
        const int b     = b0 + b_loc;

        float logits[KK];
#pragma unroll
        for (int kk = 0; kk < KK; ++kk) logits[kk] = s_c[b_loc][kk] + bmix[kk];

        float m[3];
#pragma unroll
        for (int c = 0; c < 3; ++c)
            m[c] = (k > 0) ? (s_c[b_loc][5 + (k - 1) * 3 + c] + bmean[(k - 1) * 3 + c]) : 0.f;

        float sc[6];
#pragma unroll
        for (int c = 0; c < 6; ++c)
            sc[c] = s_c[b_loc][17 + k * 6 + c] + bscale[k * 6 + c];

        float mx = logits[0];
#pragma unroll
        for (int kk = 1; kk < KK; ++kk) mx = fmaxf(mx, logits[kk]);
        float den = 0.f;
#pragma unroll
        for (int kk = 0; kk < KK; ++kk) den += expf(logits[kk] - mx);
        const float wgt = expf(logits[k] - mx) / den;

        const float L00 = softplus_f(sc[0]);
        const float L10 = sc[1];
        const float L11 = softplus_f(sc[2]);
        const float L20 = sc[3];
        const float L21 = sc[4];
        const float L22 = softplus_f(sc[5]);

        const float r00 = 1.f / L00;
        const float r11 = 1.f / L11;
        const float r22 = 1.f / L22;
        const float a   = wgt * r00 * r11 * r22 * INV_2PI_POW15;

        float* Lo = Lout + ((size_t)b * KK + k) * 9;
        Lo[0] = L00; Lo[1] = 0.f; Lo[2] = 0.f;
        Lo[3] = L10; Lo[4] = L11; Lo[5] = 0.f;
        Lo[6] = L20; Lo[7] = L21; Lo[8] = L22;

        const int pj = k * 10;
        par[(pj + 0) * BB + b] = m[0];
        par[(pj + 1) * BB + b] = m[1];
        par[(pj + 2) * BB + b] = m[2];
        par[(pj + 3) * BB + b] = r00;
        par[(pj + 4) * BB + b] = L10;
        par[(pj + 5) * BB + b] = r11;
        par[(pj + 6) * BB + b] = L20;
        par[(pj + 7) * BB + b] = L21;
        par[(pj + 8) * BB + b] = r22;
        par[(pj + 9) * BB + b] = a;
    }
}

// ---------------------------------------------------------------------------
// Kernel 2: per-(p,b) mixture density (memory-bound, at HBM floor).
// out[p*B + b] = sum_k a_k * exp(-0.5 * |L^-1 (x - mu)|^2)
// ---------------------------------------------------------------------------
__global__ __launch_bounds__(256) void eval_kernel(
    const float* __restrict__ dxyz,
    const float* __restrict__ par,
    float* __restrict__ out)
{
    const int b = blockIdx.x * 256 + threadIdx.x;

    float m0[KK], m1[KK], m2[KK], r00[KK], l10[KK], r11[KK], l20[KK], l21[KK], r22[KK], am[KK];
#pragma unroll
    for (int k = 0; k < KK; ++k) {
        const int pj = k * 10;
        m0[k]  = par[(pj + 0) * BB + b];
        m1[k]  = par[(pj + 1) * BB + b];
        m2[k]  = par[(pj + 2) * BB + b];
        r00[k] = par[(pj + 3) * BB + b];
        l10[k] = par[(pj + 4) * BB + b];
        r11[k] = par[(pj + 5) * BB + b];
        l20[k] = par[(pj + 6) * BB + b];
        l21[k] = par[(pj + 7) * BB + b];
        r22[k] = par[(pj + 8) * BB + b];
        am[k]  = par[(pj + 9) * BB + b];
    }

    const int p0 = blockIdx.y * PTS_PER_THREAD;
#pragma unroll 3
    for (int i = 0; i < PTS_PER_THREAD; ++i) {
        const int p = p0 + i;
        const size_t idx = (size_t)p * BB + b;
        const float* xv = dxyz + idx * 3;
        const float x0 = xv[0];
        const float x1 = xv[1];
        const float x2 = xv[2];

        float res = 0.f;
#pragma unroll
        for (int k = 0; k < KK; ++k) {
            const float d0 = x0 - m0[k];
            const float d1 = x1 - m1[k];
            const float d2 = x2 - m2[k];
            const float z0 = d0 * r00[k];
            const float z1 = fmaf(-l10[k], z0, d1) * r11[k];
            const float z2 = fmaf(-l21[k], z1, fmaf(-l20[k], z0, d2)) * r22[k];
            const float q  = fmaf(z2, z2, fmaf(z1, z1, z0 * z0));
            res = fmaf(am[k], __expf(-0.5f * q), res);
        }
        out[idx] = res;
    }
}

extern "C" void kernel_launch(void* const* d_in, const int* in_sizes, int n_in,
                              void* d_out, int out_size, void* d_ws, size_t ws_size,
                              hipStream_t stream) {
    const float* rep    = (const float*)d_in[0];
    const float* dxyz   = (const float*)d_in[1];
    const float* Wmix   = (const float*)d_in[2];
    const float* bmix   = (const float*)d_in[3];
    const float* Wmean  = (const float*)d_in[4];
    const float* bmean  = (const float*)d_in[5];
    const float* Wscale = (const float*)d_in[6];
    const float* bscale = (const float*)d_in[7];

    float* out  = (float*)d_out;
    float* Lout = out + (size_t)BB * PP;          // second tuple output

    float* par = (float*)d_ws;                    // 50*B f32 (819 KB)
    short* Wpk = (short*)(par + 50 * BB);         // 98304 bf16 (196 KB)

    pack_kernel<<<384, 256, 0, stream>>>(Wmix, Wmean, Wscale, Wpk);

    head_fused_kernel<<<BB / GR, 1024, 0, stream>>>(rep, Wpk, bmix, bmean, bscale, Lout, par);

    eval_kernel<<<dim3(BB / 256, PP / PTS_PER_THREAD), 256, 0, stream>>>(dxyz, par, out);
}

// Round 9
// 36.196 us; speedup vs baseline: 1.3020x; 1.0629x over previous
//
#include <hip/hip_runtime.h>
#include <math.h>

#define BB 4096
#define DD 1024
#define KK 5
#define PP 1323
#define PTS_PER_THREAD 21   // 1323 = 63 * 21

// (2*pi)^(-3/2)
#define INV_2PI_POW15 0.06349363593424097f

// ---- fused head config ----
#define GR   16       // rows per block -> 256 blocks (1 per CU)
#define NWV  16       // waves per block
#define RST  13       // s_red inner stride (12 + 1)
#define CSTR 49       // s_c inner stride
#define NG   13       // param groups of 4 (52 slots, 50 used)

typedef short  bf16x8 __attribute__((ext_vector_type(8)));
typedef float  f32x4  __attribute__((ext_vector_type(4)));

__device__ __forceinline__ short f2bf(float f) {
    union { float f; unsigned u; } x; x.f = f;
    const unsigned r = x.u + 0x7fffu + ((x.u >> 16) & 1u);  // RNE
    return (short)(r >> 16);
}
__device__ __forceinline__ float softplus_f(float x) {
    return (x > 20.f) ? x : log1pf(expf(x));
}

// ---------------------------------------------------------------------------
// Kernel 0: pack weights into bf16 MFMA fragment order (hi only):
// Wpk[chunk][nt][lane][8], element = W[k][j] where
// k = chunk*32 + (lane>>4)*8 + e, j = nt*16 + (lane&15).
// ---------------------------------------------------------------------------
__global__ __launch_bounds__(256) void pack_kernel(
    const float* __restrict__ Wmix,
    const float* __restrict__ Wmean,
    const float* __restrict__ Wscale,
    short* __restrict__ Wpk)
{
    const int e  = blockIdx.x * 256 + threadIdx.x;   // 0 .. 49151
    int r        = e;
    const int chunk = r / 1536;  r -= chunk * 1536;
    const int nt    = r / 512;   r -= nt * 512;
    const int l     = r >> 3;
    const int ee    = r & 7;

    const int k = chunk * 32 + ((l >> 4) << 3) + ee;
    const int j = nt * 16 + (l & 15);

    float v;
    if (j < 5)       v = Wmix[k * 5 + j];
    else if (j < 17) v = Wmean[k * 12 + (j - 5)];
    else if (j < 47) v = Wscale[k * 30 + (j - 17)];
    else             v = 0.f;

    Wpk[e] = f2bf(v);
}

// ---------------------------------------------------------------------------
// Kernel 1: fused head, staging-free, single-bf16. 256 blocks x 1024 thr
// (16 waves). Wave w owns k in [64w, 64w+64) (2 chunks): A-fragments direct
// from global rep, converted to bf16 in-register; B from packed Wpk
// (coalesced 1 KB per fragment). 3 MFMAs per chunk. 16-deep cross-wave LDS
// reduce, then 80-thread (b,k) tail writes L and packed par4.
// ---------------------------------------------------------------------------
__global__ __launch_bounds__(1024, 4) void head_fused_kernel(
    const float* __restrict__ rep,
    const short* __restrict__ Wpk,
    const float* __restrict__ bmix,
    const float* __restrict__ bmean,
    const float* __restrict__ bscale,
    float* __restrict__ Lout,
    float* __restrict__ par4)
{
    __shared__ float s_red[NWV][64][RST];   // 53.2 KB
    __shared__ float s_c[GR][CSTR];         // 3.1 KB

    const int t  = threadIdx.x;
    const int w  = t >> 6;          // wave 0..15
    const int l  = t & 63;
    const int lm = l & 15;
    const int lk = (l >> 4) * 8;
    const int b0 = blockIdx.x * GR;

    f32x4 acc[3] = {f32x4{0,0,0,0}, f32x4{0,0,0,0}, f32x4{0,0,0,0}};

#pragma unroll
    for (int kt = 0; kt < 2; ++kt) {
        const int chunk = w * 2 + kt;        // global 32-k chunk 0..31
        const int kof   = chunk * 32 + lk;

        // A-fragment direct from global: row b0+lm, 8 consecutive k
        const float* arow = rep + (size_t)(b0 + lm) * DD + kof;
        const f32x4 a0 = *(const f32x4*)(arow);
        const f32x4 a1 = *(const f32x4*)(arow + 4);

        bf16x8 ah;
#pragma unroll
        for (int u = 0; u < 4; ++u) {
            ah[u]     = f2bf(a0[u]);
            ah[u + 4] = f2bf(a1[u]);
        }

#pragma unroll
        for (int nt = 0; nt < 3; ++nt) {
            const bf16x8 bh = *(const bf16x8*)(Wpk + (((size_t)chunk * 3 + nt) * 64 + l) * 8);
            acc[nt] = __builtin_amdgcn_mfma_f32_16x16x32_bf16(ah, bh, acc[nt], 0, 0, 0);
        }
    }

    // ---- cross-wave reduce via LDS (16 partials) ----
#pragma unroll
    for (int nt = 0; nt < 3; ++nt)
#pragma unroll
        for (int r = 0; r < 4; ++r)
            s_red[w][l][nt * 4 + r] = acc[nt][r];
    __syncthreads();

    // cooperative sum into s_c[b_loc][j]; C layout [m89]:
    // col(=j) = lane&15, row(=b_loc) = (lane>>4)*4 + reg
    if (t < GR * 47) {
        const int b_loc = t & 15;
        const int j     = t >> 4;
        const int lane  = ((b_loc >> 2) << 4) | (j & 15);
        const int reg   = ((j >> 4) << 2) | (b_loc & 3);
        float s = 0.f;
#pragma unroll
        for (int q = 0; q < NWV; ++q) s += s_red[q][lane][reg];
        s_c[b_loc][j] = s;
    }
    __syncthreads();

    // ---- tail: 80 threads = 16 b x 5 k ----
    if (t < GR * KK) {
        const int k     = t >> 4;
        const int b_loc = t & 15;
        const int b     = b0 + b_loc;

        float logits[KK];
#pragma unroll
        for (int kk = 0; kk < KK; ++kk) logits[kk] = s_c[b_loc][kk] + bmix[kk];

        float m[3];
#pragma unroll
        for (int c = 0; c < 3; ++c)
            m[c] = (k > 0) ? (s_c[b_loc][5 + (k - 1) * 3 + c] + bmean[(k - 1) * 3 + c]) : 0.f;

        float sc[6];
#pragma unroll
        for (int c = 0; c < 6; ++c)
            sc[c] = s_c[b_loc][17 + k * 6 + c] + bscale[k * 6 + c];

        float mx = logits[0];
#pragma unroll
        for (int kk = 1; kk < KK; ++kk) mx = fmaxf(mx, logits[kk]);
        float den = 0.f;
#pragma unroll
        for (int kk = 0; kk < KK; ++kk) den += expf(logits[kk] - mx);
        const float wgt = expf(logits[k] - mx) / den;

        const float L00 = softplus_f(sc[0]);
        const float L10 = sc[1];
        const float L11 = softplus_f(sc[2]);
        const float L20 = sc[3];
        const float L21 = sc[4];
        const float L22 = softplus_f(sc[5]);

        const float r00 = 1.f / L00;
        const float r11 = 1.f / L11;
        const float r22 = 1.f / L22;
        const float a   = wgt * r00 * r11 * r22 * INV_2PI_POW15;

        float* Lo = Lout + ((size_t)b * KK + k) * 9;
        Lo[0] = L00; Lo[1] = 0.f; Lo[2] = 0.f;
        Lo[3] = L10; Lo[4] = L11; Lo[5] = 0.f;
        Lo[6] = L20; Lo[7] = L21; Lo[8] = L22;

        // packed param store: param id q = k*10 + i -> par4[(q>>2)*BB + b][q&3]
        float pv[10] = { m[0], m[1], m[2], r00, L10, r11, L20, L21, r22, a };
#pragma unroll
        for (int i = 0; i < 10; ++i) {
            const int q = k * 10 + i;
            par4[(((size_t)(q >> 2)) * BB + b) * 4 + (q & 3)] = pv[i];
        }
    }
}

// ---------------------------------------------------------------------------
// Kernel 2: per-(p,b) mixture density (memory-bound, at HBM floor).
// out[p*B + b] = sum_k a_k * exp(-0.5 * |L^-1 (x - mu)|^2)
// Params loaded as 13 coalesced f32x4.
// ---------------------------------------------------------------------------
__global__ __launch_bounds__(256) void eval_kernel(
    const float* __restrict__ dxyz,
    const float* __restrict__ par4,
    float* __restrict__ out)
{
    const int b = blockIdx.x * 256 + threadIdx.x;

    float pr[NG * 4];
#pragma unroll
    for (int g = 0; g < NG; ++g) {
        const f32x4 v = *(const f32x4*)(par4 + ((size_t)g * BB + b) * 4);
        pr[g * 4 + 0] = v[0];
        pr[g * 4 + 1] = v[1];
        pr[g * 4 + 2] = v[2];
        pr[g * 4 + 3] = v[3];
    }

    const int p0 = blockIdx.y * PTS_PER_THREAD;
#pragma unroll 3
    for (int i = 0; i < PTS_PER_THREAD; ++i) {
        const int p = p0 + i;
        const size_t idx = (size_t)p * BB + b;
        const float* xv = dxyz + idx * 3;
        const float x0 = xv[0];
        const float x1 = xv[1];
        const float x2 = xv[2];

        float res = 0.f;
#pragma unroll
        for (int k = 0; k < KK; ++k) {
            const float d0 = x0 - pr[k * 10 + 0];
            const float d1 = x1 - pr[k * 10 + 1];
            const float d2 = x2 - pr[k * 10 + 2];
            const float z0 = d0 * pr[k * 10 + 3];
            const float z1 = fmaf(-pr[k * 10 + 4], z0, d1) * pr[k * 10 + 5];
            const float z2 = fmaf(-pr[k * 10 + 7], z1, fmaf(-pr[k * 10 + 6], z0, d2)) * pr[k * 10 + 8];
            const float q  = fmaf(z2, z2, fmaf(z1, z1, z0 * z0));
            res = fmaf(pr[k * 10 + 9], __expf(-0.5f * q), res);
        }
        out[idx] = res;
    }
}

extern "C" void kernel_launch(void* const* d_in, const int* in_sizes, int n_in,
                              void* d_out, int out_size, void* d_ws, size_t ws_size,
                              hipStream_t stream) {
    const float* rep    = (const float*)d_in[0];
    const float* dxyz   = (const float*)d_in[1];
    const float* Wmix   = (const float*)d_in[2];
    const float* bmix   = (const float*)d_in[3];
    const float* Wmean  = (const float*)d_in[4];
    const float* bmean  = (const float*)d_in[5];
    const float* Wscale = (const float*)d_in[6];
    const float* bscale = (const float*)d_in[7];

    float* out  = (float*)d_out;
    float* Lout = out + (size_t)BB * PP;          // second tuple output

    float* par4 = (float*)d_ws;                   // NG*BB*4 f32 (852 KB)
    short* Wpk  = (short*)(par4 + (size_t)NG * BB * 4);  // 49152 bf16 (98 KB)

    pack_kernel<<<192, 256, 0, stream>>>(Wmix, Wmean, Wscale, Wpk);

    head_fused_kernel<<<BB / GR, 1024, 0, stream>>>(rep, Wpk, bmix, bmean, bscale, Lout, par4);

    eval_kernel<<<dim3(BB / 256, PP / PTS_PER_THREAD), 256, 0, stream>>>(dxyz, par4, out);
}

// Round 10
// 35.919 us; speedup vs baseline: 1.3120x; 1.0077x over previous
//
#include <hip/hip_runtime.h>
#include <math.h>

#define BB 4096
#define DD 1024
#define KK 5
#define PP 1323
#define PTS_PER_THREAD 7    // 1323 = 189 * 7
#define GYB 189

// (2*pi)^(-3/2)
#define INV_2PI_POW15 0.06349363593424097f

// ---- fused head config ----
#define GR   16       // rows per block -> 256 blocks (1 per CU)
#define NWV  16       // waves per block
#define RST  13       // s_red inner stride (12 + 1)
#define CSTR 49       // s_c inner stride
#define NG   13       // param groups of 4 (52 slots, 50 used)

typedef short  bf16x8 __attribute__((ext_vector_type(8)));
typedef float  f32x4  __attribute__((ext_vector_type(4)));

__device__ __forceinline__ short f2bf(float f) {
    union { float f; unsigned u; } x; x.f = f;
    const unsigned r = x.u + 0x7fffu + ((x.u >> 16) & 1u);  // RNE
    return (short)(r >> 16);
}
__device__ __forceinline__ float softplus_f(float x) {
    return (x > 20.f) ? x : log1pf(expf(x));
}

__device__ __forceinline__ int wpk_index(int k, int j) {
    // Wpk[chunk][nt][lane][8]: k = chunk*32 + (lane>>4)*8 + ee, j = nt*16 + (lane&15)
    const int chunk = k >> 5;
    const int kin   = k & 31;
    const int lane  = ((kin >> 3) << 4) | (j & 15);
    const int nt    = j >> 4;
    const int ee    = k & 7;
    return ((chunk * 3 + nt) * 64 + lane) * 8 + ee;
}

// ---------------------------------------------------------------------------
// Kernel 0: pack weights -> bf16 MFMA fragment order, COALESCED READS
// (linear over each source array), scattered 2-B writes (98 KB total, L2).
// ---------------------------------------------------------------------------
__global__ __launch_bounds__(256) void pack_kernel(
    const float* __restrict__ Wmix,
    const float* __restrict__ Wmean,
    const float* __restrict__ Wscale,
    short* __restrict__ Wpk)
{
    const int t = blockIdx.x * 256 + threadIdx.x;   // 0 .. 49151
    int k, j; float v;
    if (t < 5120) {                       // Wmix: [1024][5]
        k = t / 5;  j = t - k * 5;
        v = Wmix[t];
    } else if (t < 17408) {               // Wmean: [1024][12]
        const int i = t - 5120;
        k = i / 12; j = 5 + (i - k * 12);
        v = Wmean[i];
    } else if (t < 48128) {               // Wscale: [1024][30]
        const int i = t - 17408;
        k = i / 30; j = 17 + (i - k * 30);
        v = Wscale[i];
    } else {                              // zero-fill j = 47
        k = t - 48128; j = 47; v = 0.f;
    }
    Wpk[wpk_index(k, j)] = f2bf(v);
}

// ---------------------------------------------------------------------------
// Kernel 1: fused head, staging-free, single-bf16. 256 blocks x 1024 thr
// (16 waves = 16 k-slices). A-fragments direct from global rep; B from
// packed Wpk (coalesced). 16-deep cross-wave LDS reduce; 80-thread (b,k)
// tail computes params; L staged in LDS then written COALESCED by 720 thr.
// ---------------------------------------------------------------------------
__global__ __launch_bounds__(1024, 4) void head_fused_kernel(
    const float* __restrict__ rep,
    const short* __restrict__ Wpk,
    const float* __restrict__ bmix,
    const float* __restrict__ bmean,
    const float* __restrict__ bscale,
    float* __restrict__ Lout,
    float* __restrict__ par4)
{
    __shared__ float s_red[NWV][64][RST];   // 53.2 KB
    __shared__ float s_c[GR][CSTR];         // 3.1 KB
    __shared__ float s_L[GR][KK][6];        // 1.9 KB

    const int t  = threadIdx.x;
    const int w  = t >> 6;          // wave 0..15
    const int l  = t & 63;
    const int lm = l & 15;
    const int lk = (l >> 4) * 8;
    const int b0 = blockIdx.x * GR;

    f32x4 acc[3] = {f32x4{0,0,0,0}, f32x4{0,0,0,0}, f32x4{0,0,0,0}};

#pragma unroll
    for (int kt = 0; kt < 2; ++kt) {
        const int chunk = w * 2 + kt;        // global 32-k chunk 0..31
        const int kof   = chunk * 32 + lk;

        const float* arow = rep + (size_t)(b0 + lm) * DD + kof;
        const f32x4 a0 = *(const f32x4*)(arow);
        const f32x4 a1 = *(const f32x4*)(arow + 4);

        bf16x8 ah;
#pragma unroll
        for (int u = 0; u < 4; ++u) {
            ah[u]     = f2bf(a0[u]);
            ah[u + 4] = f2bf(a1[u]);
        }

#pragma unroll
        for (int nt = 0; nt < 3; ++nt) {
            const bf16x8 bh = *(const bf16x8*)(Wpk + (((size_t)chunk * 3 + nt) * 64 + l) * 8);
            acc[nt] = __builtin_amdgcn_mfma_f32_16x16x32_bf16(ah, bh, acc[nt], 0, 0, 0);
        }
    }

    // ---- cross-wave reduce via LDS (16 partials) ----
#pragma unroll
    for (int nt = 0; nt < 3; ++nt)
#pragma unroll
        for (int r = 0; r < 4; ++r)
            s_red[w][l][nt * 4 + r] = acc[nt][r];
    __syncthreads();

    // cooperative sum into s_c[b_loc][j]; C layout [m89]:
    // col(=j) = lane&15, row(=b_loc) = (lane>>4)*4 + reg
    if (t < GR * 47) {
        const int b_loc = t & 15;
        const int j     = t >> 4;
        const int lane  = ((b_loc >> 2) << 4) | (j & 15);
        const int reg   = ((j >> 4) << 2) | (b_loc & 3);
        float s = 0.f;
#pragma unroll
        for (int q = 0; q < NWV; ++q) s += s_red[q][lane][reg];
        s_c[b_loc][j] = s;
    }
    __syncthreads();

    // ---- tail: 80 threads = 16 b x 5 k -> params + s_L ----
    if (t < GR * KK) {
        const int k     = t >> 4;
        const int b_loc = t & 15;
        const int b     = b0 + b_loc;

        float logits[KK];
#pragma unroll
        for (int kk = 0; kk < KK; ++kk) logits[kk] = s_c[b_loc][kk] + bmix[kk];

        float m[3];
#pragma unroll
        for (int c = 0; c < 3; ++c)
            m[c] = (k > 0) ? (s_c[b_loc][5 + (k - 1) * 3 + c] + bmean[(k - 1) * 3 + c]) : 0.f;

        float sc[6];
#pragma unroll
        for (int c = 0; c < 6; ++c)
            sc[c] = s_c[b_loc][17 + k * 6 + c] + bscale[k * 6 + c];

        float mx = logits[0];
#pragma unroll
        for (int kk = 1; kk < KK; ++kk) mx = fmaxf(mx, logits[kk]);
        float den = 0.f;
#pragma unroll
        for (int kk = 0; kk < KK; ++kk) den += expf(logits[kk] - mx);
        const float wgt = expf(logits[k] - mx) / den;

        const float L00 = softplus_f(sc[0]);
        const float L10 = sc[1];
        const float L11 = softplus_f(sc[2]);
        const float L20 = sc[3];
        const float L21 = sc[4];
        const float L22 = softplus_f(sc[5]);

        const float r00 = 1.f / L00;
        const float r11 = 1.f / L11;
        const float r22 = 1.f / L22;
        const float a   = wgt * r00 * r11 * r22 * INV_2PI_POW15;

        s_L[b_loc][k][0] = L00;
        s_L[b_loc][k][1] = L10;
        s_L[b_loc][k][2] = L11;
        s_L[b_loc][k][3] = L20;
        s_L[b_loc][k][4] = L21;
        s_L[b_loc][k][5] = L22;

        // packed param store: q = k*10 + i -> par4[(q>>2)*BB + b][q&3]
        float pv[10] = { m[0], m[1], m[2], r00, L10, r11, L20, L21, r22, a };
#pragma unroll
        for (int i = 0; i < 10; ++i) {
            const int q = k * 10 + i;
            par4[(((size_t)(q >> 2)) * BB + b) * 4 + (q & 3)] = pv[i];
        }
    }
    __syncthreads();

    // ---- coalesced Lout write: 720 contiguous floats = 16 b x 5 k x 9 ----
    if (t < GR * KK * 9) {
        const int b_loc = t / 45;
        const int rem   = t - b_loc * 45;
        const int k     = rem / 9;
        const int e9    = rem - k * 9;
        const int rr    = e9 / 3;
        const int cc    = e9 - rr * 3;
        const float v = (cc > rr) ? 0.f : s_L[b_loc][k][(rr * (rr + 1)) / 2 + cc];
        Lout[(size_t)b0 * 45 + t] = v;
    }
}

// ---------------------------------------------------------------------------
// Kernel 2: per-(p,b) mixture density. PTS=7 -> 3x more waves for latency
// hiding. Params as 13 coalesced f32x4 (L2-resident).
// ---------------------------------------------------------------------------
__global__ __launch_bounds__(256) void eval_kernel(
    const float* __restrict__ dxyz,
    const float* __restrict__ par4,
    float* __restrict__ out)
{
    const int b = blockIdx.x * 256 + threadIdx.x;

    float pr[NG * 4];
#pragma unroll
    for (int g = 0; g < NG; ++g) {
        const f32x4 v = *(const f32x4*)(par4 + ((size_t)g * BB + b) * 4);
        pr[g * 4 + 0] = v[0];
        pr[g * 4 + 1] = v[1];
        pr[g * 4 + 2] = v[2];
        pr[g * 4 + 3] = v[3];
    }

    const int p0 = blockIdx.y * PTS_PER_THREAD;
#pragma unroll
    for (int i = 0; i < PTS_PER_THREAD; ++i) {
        const int p = p0 + i;
        const size_t idx = (size_t)p * BB + b;
        const float* xv = dxyz + idx * 3;
        const float x0 = xv[0];
        const float x1 = xv[1];
        const float x2 = xv[2];

        float res = 0.f;
#pragma unroll
        for (int k = 0; k < KK; ++k) {
            const float d0 = x0 - pr[k * 10 + 0];
            const float d1 = x1 - pr[k * 10 + 1];
            const float d2 = x2 - pr[k * 10 + 2];
            const float z0 = d0 * pr[k * 10 + 3];
            const float z1 = fmaf(-pr[k * 10 + 4], z0, d1) * pr[k * 10 + 5];
            const float z2 = fmaf(-pr[k * 10 + 7], z1, fmaf(-pr[k * 10 + 6], z0, d2)) * pr[k * 10 + 8];
            const float q  = fmaf(z2, z2, fmaf(z1, z1, z0 * z0));
            res = fmaf(pr[k * 10 + 9], __expf(-0.5f * q), res);
        }
        out[idx] = res;
    }
}

extern "C" void kernel_launch(void* const* d_in, const int* in_sizes, int n_in,
                              void* d_out, int out_size, void* d_ws, size_t ws_size,
                              hipStream_t stream) {
    const float* rep    = (const float*)d_in[0];
    const float* dxyz   = (const float*)d_in[1];
    const float* Wmix   = (const float*)d_in[2];
    const float* bmix   = (const float*)d_in[3];
    const float* Wmean  = (const float*)d_in[4];
    const float* bmean  = (const float*)d_in[5];
    const float* Wscale = (const float*)d_in[6];
    const float* bscale = (const float*)d_in[7];

    float* out  = (float*)d_out;
    float* Lout = out + (size_t)BB * PP;          // second tuple output

    float* par4 = (float*)d_ws;                   // NG*BB*4 f32 (852 KB)
    short* Wpk  = (short*)(par4 + (size_t)NG * BB * 4);  // 49152 bf16 (98 KB)

    pack_kernel<<<192, 256, 0, stream>>>(Wmix, Wmean, Wscale, Wpk);

    head_fused_kernel<<<BB / GR, 1024, 0, stream>>>(rep, Wpk, bmix, bmean, bscale, Lout, par4);

    eval_kernel<<<dim3(BB / 256, GYB), 256, 0, stream>>>(dxyz, par4, out);
}